// Round 2
// 525.610 us; speedup vs baseline: 1.1759x; 1.1759x over previous
//
#include <hip/hip_runtime.h>
#include <cstdint>

#define P2 2654435761u
#define P3 805459861u
#define HMASK 524287u

// Native clang vector types -- __builtin_nontemporal_* requires these
// (HIP_vector_type float4/float2 are structs and are rejected).
typedef float nfloat4 __attribute__((ext_vector_type(4)));
typedef float nfloat2 __attribute__((ext_vector_type(2)));

// int(16 * exp((ln2048-ln16)/15)**l), hand-verified against IEEE-double
// semantics of the numpy reference. NOTE res[7]=153 (153.987) and
// res[15]=2048 (2048.0000000000036 -> min-clamped).
// All values EVEN => rm1 odd => even x0 is never at the clamp boundary,
// which the x-pair merge below relies on.
__constant__ int RES[16] = {16, 22, 30, 42, 58, 80, 111, 153,
                            212, 294, 406, 561, 776, 1072, 1482, 2048};

// One thread per (point, level). t = i*16 + l, point-major so the final
// float2 store is perfectly coalesced.
//
// Key trick: hash = x ^ y*P2 ^ z*P3 with prime 1 on x, so for even x0 the
// two x-corners hash to {h, h^1} -- the same 16B-aligned float4 pair in the
// table. 4 float4 gathers replace 8 float2 gathers for ~half the threads.
__global__ __launch_bounds__(256) void hash_enc_kernel(
    const float* __restrict__ pos, const float2* __restrict__ tbl,
    float2* __restrict__ out, int n)
{
    const float4* __restrict__ tbl4 = (const float4*)tbl;

    __shared__ int sres[16];
    __shared__ float spos[48];   // 16 points * 3 coords for this block

    const int tid = threadIdx.x;
    if (tid < 16) sres[tid] = RES[tid];

    // Stage the block's 16 positions: 12 float4 nt loads instead of
    // 768 broadcast lane-requests (positions are read-once -> nt keeps
    // L2 free for the hash table).
    const int p0 = blockIdx.x * 16;          // first point of this block
    if (p0 + 16 <= n) {
        if (tid < 12) {
            nfloat4 v = __builtin_nontemporal_load(
                (const nfloat4*)(pos + (size_t)p0 * 3) + tid);
            ((nfloat4*)spos)[tid] = v;
        }
    } else {
        if (tid < 48) {
            int gi = p0 * 3 + tid;
            spos[tid] = (gi < 3 * n) ? pos[gi] : 0.0f;
        }
    }
    __syncthreads();

    const int t = blockIdx.x * 256 + tid;
    const int i = t >> 4;        // point index
    const int l = t & 15;        // level index
    if (i >= n) return;
    const int li = tid >> 4;     // local point 0..15

    // 16 lanes with same li broadcast from LDS (conflict-free)
    float x = (spos[3 * li + 0] + 1.0f) * 0.5f;
    float y = (spos[3 * li + 1] + 1.0f) * 0.5f;
    float z = (spos[3 * li + 2] + 1.0f) * 0.5f;

    const int rm1 = sres[l] - 1;
    const float rf = (float)rm1;

    float sx = x * rf, sy = y * rf, sz = z * rf;
    float fx = floorf(sx), fy = floorf(sy), fz = floorf(sz);
    float wx = sx - fx, wy = sy - fy, wz = sz - fz;
    int x0 = (int)fx, y0 = (int)fy, z0 = (int)fz;
    int x0c = min(max(x0, 0), rm1), x1c = min(max(x0 + 1, 0), rm1);
    int y0c = min(max(y0, 0), rm1), y1c = min(max(y0 + 1, 0), rm1);
    int z0c = min(max(z0, 0), rm1), z1c = min(max(z0 + 1, 0), rm1);

    // low 19 bits of the int64 hash == low 19 bits of the uint32 hash
    uint32_t hy0 = (uint32_t)y0c * P2, hy1 = (uint32_t)y1c * P2;
    uint32_t hz0 = (uint32_t)z0c * P3, hz1 = (uint32_t)z1c * P3;
    uint32_t m00 = hy0 ^ hz0;   // (y0,z0)
    uint32_t m01 = hy0 ^ hz1;   // (y0,z1)
    uint32_t m10 = hy1 ^ hz0;   // (y1,z0)
    uint32_t m11 = hy1 ^ hz1;   // (y1,z1)

    uint32_t hx0 = (uint32_t)x0c;
    uint32_t j000 = (hx0 ^ m00) & HMASK;
    uint32_t j001 = (hx0 ^ m01) & HMASK;
    uint32_t j010 = (hx0 ^ m10) & HMASK;
    uint32_t j011 = (hx0 ^ m11) & HMASK;

    // 4 pair loads: each holds the x0 corner in one half; when x0 is even
    // the other half IS the x1 corner (h^1). All independent -> one
    // latency exposure.
    float4 q00 = tbl4[j000 >> 1];
    float4 q01 = tbl4[j001 >> 1];
    float4 q10 = tbl4[j010 >> 1];
    float4 q11 = tbl4[j011 >> 1];

    float2 c000, c001, c010, c011, c100, c101, c110, c111;
    bool b00 = (j000 & 1), b01 = (j001 & 1), b10 = (j010 & 1), b11 = (j011 & 1);
    c000 = b00 ? make_float2(q00.z, q00.w) : make_float2(q00.x, q00.y);
    c100 = b00 ? make_float2(q00.x, q00.y) : make_float2(q00.z, q00.w);
    c001 = b01 ? make_float2(q01.z, q01.w) : make_float2(q01.x, q01.y);
    c101 = b01 ? make_float2(q01.x, q01.y) : make_float2(q01.z, q01.w);
    c010 = b10 ? make_float2(q10.z, q10.w) : make_float2(q10.x, q10.y);
    c110 = b10 ? make_float2(q10.x, q10.y) : make_float2(q10.z, q10.w);
    c011 = b11 ? make_float2(q11.z, q11.w) : make_float2(q11.x, q11.y);
    c111 = b11 ? make_float2(q11.x, q11.y) : make_float2(q11.z, q11.w);

    // Odd x0: the pair's other half is NOT the x1 corner -- fetch the true
    // x1 corners under exec mask (only odd lanes issue requests).
    if (x0c & 1) {
        uint32_t hx1 = (uint32_t)x1c;
        c100 = tbl[(hx1 ^ m00) & HMASK];
        c101 = tbl[(hx1 ^ m01) & HMASK];
        c110 = tbl[(hx1 ^ m10) & HMASK];
        c111 = tbl[(hx1 ^ m11) & HMASK];
    }

    float ux = 1.0f - wx, uy = 1.0f - wy, uz = 1.0f - wz;
    float w00 = ux * uy, w01 = ux * wy, w10 = wx * uy, w11 = wx * wy;
    float f0, f1;
    f0  = (w00 * uz) * c000.x; f1  = (w00 * uz) * c000.y;
    f0 += (w00 * wz) * c001.x; f1 += (w00 * wz) * c001.y;
    f0 += (w01 * uz) * c010.x; f1 += (w01 * uz) * c010.y;
    f0 += (w01 * wz) * c011.x; f1 += (w01 * wz) * c011.y;
    f0 += (w10 * uz) * c100.x; f1 += (w10 * uz) * c100.y;
    f0 += (w10 * wz) * c101.x; f1 += (w10 * wz) * c101.y;
    f0 += (w11 * uz) * c110.x; f1 += (w11 * uz) * c110.y;
    f0 += (w11 * wz) * c111.x; f1 += (w11 * wz) * c111.y;

    // Output is 134 MB write-once: nontemporal so it doesn't evict the
    // 4 MB table from L2 (FETCH_SIZE showed ~160 MB of table re-fetch).
    nfloat2 r; r.x = f0; r.y = f1;
    __builtin_nontemporal_store(r, (nfloat2*)&out[t]);
}

extern "C" void kernel_launch(void* const* d_in, const int* in_sizes, int n_in,
                              void* d_out, int out_size, void* d_ws, size_t ws_size,
                              hipStream_t stream) {
    const float* pos = (const float*)d_in[0];
    const float2* tbl = (const float2*)d_in[1];
    float2* out = (float2*)d_out;
    int n = in_sizes[0] / 3;
    long long total = (long long)n * 16;
    dim3 grid((unsigned)((total + 255) / 256)), block(256);
    hash_enc_kernel<<<grid, block, 0, stream>>>(pos, tbl, out, n);
}